// Round 9
// baseline (449.824 us; speedup 1.0000x reference)
//
#include <hip/hip_runtime.h>

// ---------------------------------------------------------------------------
// AttentionThinkingBlock: LN1 -> QKV -> causal attn -> proj+res -> LN2 -> MLP
// B=2, S=2048, D=1024, H=16, HS=64.  All internal matmuls in bf16 MFMA.
// Round 7: attn residency was capped at ~2 blocks/CU (27.6KB LDS/block);
// K/V are XCD-L2-resident (512KB/bh), so drop K/V LDS staging entirely --
// read MFMA fragments from L2 directly.  LDS 27.6KB -> 9.2KB, zero barriers.
// ---------------------------------------------------------------------------

typedef __bf16 bf16_t;
typedef __attribute__((ext_vector_type(8))) __bf16 bf16x8;
typedef __attribute__((ext_vector_type(4))) __bf16 bf16x4;
typedef __attribute__((ext_vector_type(4))) float f32x4;

__device__ __forceinline__ f32x4 mfma16(bf16x8 a, bf16x8 b, f32x4 c) {
  return __builtin_amdgcn_mfma_f32_16x16x32_bf16(a, b, c, 0, 0, 0);
}

__device__ __forceinline__ void gll16(const void* g, void* l) {
  __builtin_amdgcn_global_load_lds(
      (const __attribute__((address_space(1))) void*)g,
      (__attribute__((address_space(3))) void*)l, 16, 0, 0);
}

// ---------------------------------------------------------------------------
// LayerNorm (f32 in) -> bf16 out.  One block per row, D=1024.
// ---------------------------------------------------------------------------
__global__ __launch_bounds__(256) void ln_kernel(
    const float* __restrict__ x, const float* __restrict__ g,
    const float* __restrict__ be, bf16_t* __restrict__ out) {
  const int row = blockIdx.x;
  const int tid = threadIdx.x;
  const float4 v = *(reinterpret_cast<const float4*>(x + (size_t)row * 1024) + tid);
  float s1 = v.x + v.y + v.z + v.w;
  float s2 = v.x * v.x + v.y * v.y + v.z * v.z + v.w * v.w;
#pragma unroll
  for (int off = 1; off < 64; off <<= 1) {
    s1 += __shfl_xor(s1, off);
    s2 += __shfl_xor(s2, off);
  }
  __shared__ float red[8];
  const int l = tid & 63, w = tid >> 6;
  if (l == 0) { red[w] = s1; red[w + 4] = s2; }
  __syncthreads();
  s1 = red[0] + red[1] + red[2] + red[3];
  s2 = red[4] + red[5] + red[6] + red[7];
  const float mu = s1 * (1.f / 1024.f);
  const float var = s2 * (1.f / 1024.f) - mu * mu;
  const float rstd = rsqrtf(var + 1e-5f);
  const float4 gg = *(reinterpret_cast<const float4*>(g) + tid);
  const float4 bb = *(reinterpret_cast<const float4*>(be) + tid);
  bf16x4 o;
  o[0] = (bf16_t)((v.x - mu) * rstd * gg.x + bb.x);
  o[1] = (bf16_t)((v.y - mu) * rstd * gg.y + bb.y);
  o[2] = (bf16_t)((v.z - mu) * rstd * gg.z + bb.z);
  o[3] = (bf16_t)((v.w - mu) * rstd * gg.w + bb.w);
  *(reinterpret_cast<bf16x4*>(out + (size_t)row * 1024) + tid) = o;
}

// ---------------------------------------------------------------------------
// Fused: h = p0 + p1 + bproj + x  (proj split-K reduce) -> hbuf f32, then LN2.
// ---------------------------------------------------------------------------
__global__ __launch_bounds__(256) void ln2_red_kernel(
    const float* __restrict__ p, const float* __restrict__ bp,
    const float* __restrict__ x, const float* __restrict__ g,
    const float* __restrict__ be, float* __restrict__ hb,
    bf16_t* __restrict__ out) {
  const size_t PM = (size_t)4096 * 1024;
  const int row = blockIdx.x;
  const int tid = threadIdx.x;
  const size_t ro = (size_t)row * 1024;
  float4 v = *(reinterpret_cast<const float4*>(p + ro) + tid);
  const float4 v1 = *(reinterpret_cast<const float4*>(p + PM + ro) + tid);
  const float4 vb = *(reinterpret_cast<const float4*>(bp) + tid);
  const float4 vx = *(reinterpret_cast<const float4*>(x + ro) + tid);
  v.x += v1.x + vb.x + vx.x; v.y += v1.y + vb.y + vx.y;
  v.z += v1.z + vb.z + vx.z; v.w += v1.w + vb.w + vx.w;
  *(reinterpret_cast<float4*>(hb + ro) + tid) = v;
  float s1 = v.x + v.y + v.z + v.w;
  float s2 = v.x * v.x + v.y * v.y + v.z * v.z + v.w * v.w;
#pragma unroll
  for (int off = 1; off < 64; off <<= 1) {
    s1 += __shfl_xor(s1, off);
    s2 += __shfl_xor(s2, off);
  }
  __shared__ float red[8];
  const int l = tid & 63, w = tid >> 6;
  if (l == 0) { red[w] = s1; red[w + 4] = s2; }
  __syncthreads();
  s1 = red[0] + red[1] + red[2] + red[3];
  s2 = red[4] + red[5] + red[6] + red[7];
  const float mu = s1 * (1.f / 1024.f);
  const float var = s2 * (1.f / 1024.f) - mu * mu;
  const float rstd = rsqrtf(var + 1e-5f);
  const float4 gg = *(reinterpret_cast<const float4*>(g) + tid);
  const float4 bb = *(reinterpret_cast<const float4*>(be) + tid);
  bf16x4 o;
  o[0] = (bf16_t)((v.x - mu) * rstd * gg.x + bb.x);
  o[1] = (bf16_t)((v.y - mu) * rstd * gg.y + bb.y);
  o[2] = (bf16_t)((v.z - mu) * rstd * gg.z + bb.z);
  o[3] = (bf16_t)((v.w - mu) * rstd * gg.w + bb.w);
  *(reinterpret_cast<bf16x4*>(out + ro) + tid) = o;
}

// ---------------------------------------------------------------------------
// FF2 split-K reduce: out = p0+p1+p2+p3 + b2 + hbuf.
// ---------------------------------------------------------------------------
__global__ __launch_bounds__(256) void red4_kernel(
    const float* __restrict__ p, const float* __restrict__ b2,
    const float* __restrict__ hb, float* __restrict__ out) {
  const size_t PM = (size_t)4096 * 1024;
  const int row = blockIdx.x;
  const int tid = threadIdx.x;
  const size_t ro = (size_t)row * 1024;
  float4 v = *(reinterpret_cast<const float4*>(p + ro) + tid);
#pragma unroll
  for (int s = 1; s < 4; s++) {
    const float4 vs = *(reinterpret_cast<const float4*>(p + s * PM + ro) + tid);
    v.x += vs.x; v.y += vs.y; v.z += vs.z; v.w += vs.w;
  }
  const float4 vb = *(reinterpret_cast<const float4*>(b2) + tid);
  const float4 vh = *(reinterpret_cast<const float4*>(hb + ro) + tid);
  v.x += vb.x + vh.x; v.y += vb.y + vh.y;
  v.z += vb.z + vh.z; v.w += vb.w + vh.w;
  *(reinterpret_cast<float4*>(out + ro) + tid) = v;
}

// ---------------------------------------------------------------------------
// Batched transpose+convert: in f32 [bz][R][C] -> out bf16 [bz][C][R]
// ---------------------------------------------------------------------------
__global__ __launch_bounds__(256) void transpose_cvt(
    const float* __restrict__ in, bf16_t* __restrict__ out, int R, int C) {
  __shared__ float t[32][33];
  const int bz = blockIdx.z;
  in += (size_t)bz * R * C;
  out += (size_t)bz * R * C;
  const int c0 = blockIdx.x * 32, r0 = blockIdx.y * 32;
  const int tx = threadIdx.x, ty = threadIdx.y;
#pragma unroll
  for (int i = 0; i < 4; i++)
    t[ty + i * 8][tx] = in[(size_t)(r0 + ty + i * 8) * C + c0 + tx];
  __syncthreads();
#pragma unroll
  for (int i = 0; i < 4; i++)
    out[(size_t)(c0 + ty + i * 8) * R + r0 + tx] = (bf16_t)t[tx][ty + i * 8];
}

// ---------------------------------------------------------------------------
// GEMM C[M,N] = A[M,K] @ B^T[N,K]  (m97 structure + XCD-aware block swizzle)
// MODE 0 = QKV epilogue  MODE 1 = f32 out = acc+bias+resid  MODE 2 = relu bf16
// MODE 3 = split-K partial (blockIdx.z chunk -> out0 + z*M*N)
// ---------------------------------------------------------------------------
template <int MODE>
__global__ __launch_bounds__(256) void gemm_bt(
    const bf16_t* __restrict__ A, const bf16_t* __restrict__ BT,
    const float* __restrict__ bias, const float* __restrict__ resid,
    void* __restrict__ out0, void* __restrict__ out1, int M, int N, int K) {
  __shared__ __align__(16) bf16_t Al[128 * 32];
  __shared__ __align__(16) bf16_t Bl[128 * 32];
  const int tid = threadIdx.x;
  const int l = tid & 63, w = tid >> 6;
  const int wr = w >> 1, wc = w & 1;
  const int lr = l & 15, lg = l >> 4;
  const int gx = gridDim.x;
  const int nwg = gx * gridDim.y;
  int flat = blockIdx.y * gx + blockIdx.x;
  flat = (flat & 7) * (nwg >> 3) + (flat >> 3);
  const int bm = (flat / gx) * 128, bn = (flat % gx) * 128;

  int k0 = 0, nK = K >> 5;
  if constexpr (MODE == 3) {
    const int chunk = K / gridDim.z;
    k0 = blockIdx.z * chunk;
    nK = chunk >> 5;
  }

  f32x4 acc[4][4];
#pragma unroll
  for (int i = 0; i < 4; i++)
#pragma unroll
    for (int j = 0; j < 4; j++) acc[i][j] = (f32x4)(0.f);

  const char* Ag = (const char*)(A + (size_t)bm * K + k0);
  const char* Bg = (const char*)(BT + (size_t)bn * K + k0);
  const size_t rowb = (size_t)K * 2;

  for (int kt = 0; kt < nK; ++kt) {
#pragma unroll
    for (int i = 0; i < 2; i++) {
      const int s = i * 256 + tid;
      const size_t go = (size_t)(s >> 2) * rowb + (size_t)(kt * 64 + (s & 3) * 16);
      gll16(Ag + go, (char*)Al + (i * 256 + w * 64) * 16);
      gll16(Bg + go, (char*)Bl + (i * 256 + w * 64) * 16);
    }
    __syncthreads();
    bf16x8 af[4], bfr[4];
#pragma unroll
    for (int mi = 0; mi < 4; mi++)
      af[mi] = *reinterpret_cast<const bf16x8*>(Al + (wr * 64 + mi * 16 + lr) * 32 + lg * 8);
#pragma unroll
    for (int ni = 0; ni < 4; ni++)
      bfr[ni] = *reinterpret_cast<const bf16x8*>(Bl + (wc * 64 + ni * 16 + lr) * 32 + lg * 8);
#pragma unroll
    for (int mi = 0; mi < 4; mi++)
#pragma unroll
      for (int ni = 0; ni < 4; ni++)
        acc[mi][ni] = mfma16(af[mi], bfr[ni], acc[mi][ni]);
    __syncthreads();
  }

#pragma unroll
  for (int mi = 0; mi < 4; mi++) {
    const int r = bm + wr * 64 + mi * 16 + lg * 4;
#pragma unroll
    for (int ni = 0; ni < 4; ni++) {
      const int c = bn + wc * 64 + ni * 16 + lr;
      f32x4 v = acc[mi][ni];
      if constexpr (MODE == 1) {
        const float bb = bias[c];
        float* o = (float*)out0;
#pragma unroll
        for (int j = 0; j < 4; j++)
          o[(size_t)(r + j) * N + c] = v[j] + bb + resid[(size_t)(r + j) * N + c];
      } else if constexpr (MODE == 2) {
        const float bb = bias[c];
        bf16_t* o = (bf16_t*)out0;
#pragma unroll
        for (int j = 0; j < 4; j++)
          o[(size_t)(r + j) * N + c] = (bf16_t)fmaxf(v[j] + bb, 0.f);
      } else if constexpr (MODE == 3) {
        float* o = (float*)out0 + (size_t)blockIdx.z * M * N;
#pragma unroll
        for (int j = 0; j < 4; j++)
          o[(size_t)(r + j) * N + c] = v[j];
      } else {
        if (c < 2048) {
          bf16_t* o = (bf16_t*)out0;
#pragma unroll
          for (int j = 0; j < 4; j++)
            o[(size_t)(r + j) * 2048 + c] = (bf16_t)v[j];
        } else {
          const int nn = c - 2048;
          const int bI = r >> 11, tl = r & 2047;
          bf16x4 pk;
#pragma unroll
          for (int j = 0; j < 4; j++) pk[j] = (bf16_t)v[j];
          *reinterpret_cast<bf16x4*>((bf16_t*)out1 +
              ((size_t)(bI * 1024 + nn)) * 2048 + tl) = pk;
        }
      }
    }
  }
}

// ---------------------------------------------------------------------------
// One K-tile of flash attention for one wave's 16 Q-rows.
// K/V fragments read DIRECTLY from global (L2-resident via XCD pinning).
// kg2: K base [t][2048-strided], vg: V^T base [hs][2048-strided].
// ---------------------------------------------------------------------------
__device__ __forceinline__ void attn_tile(
    const bf16_t* __restrict__ kg2, const bf16_t* __restrict__ vg,
    const int st, bf16_t* __restrict__ plw, const bf16x8* qf, f32x4* oacc,
    float* mrow, float* lrow, const int lr, const int lg,
    const int rbase, const bool diag) {
  const int cbase = st * 64;
  f32x4 sc4[4];
#pragma unroll
  for (int ct = 0; ct < 4; ct++) sc4[ct] = (f32x4)(0.f);
#pragma unroll
  for (int ct = 0; ct < 4; ct++)
#pragma unroll
    for (int kc = 0; kc < 2; kc++) {
      const bf16x8 kf = *reinterpret_cast<const bf16x8*>(
          kg2 + (size_t)(cbase + ct * 16 + lr) * 2048 + kc * 32 + lg * 8);
      sc4[ct] = mfma16(qf[kc], kf, sc4[ct]);
    }
#pragma unroll
  for (int ct = 0; ct < 4; ct++)
#pragma unroll
    for (int j = 0; j < 4; j++) {
      float sv = sc4[ct][j] * 0.125f;
      if (diag && (cbase + ct * 16 + lr > rbase + j)) sv = -1e30f;
      sc4[ct][j] = sv;
    }
  float rmax[4];
#pragma unroll
  for (int j = 0; j < 4; j++)
    rmax[j] = fmaxf(fmaxf(sc4[0][j], sc4[1][j]), fmaxf(sc4[2][j], sc4[3][j]));
#pragma unroll
  for (int off = 1; off < 16; off <<= 1)
#pragma unroll
    for (int j = 0; j < 4; j++) rmax[j] = fmaxf(rmax[j], __shfl_xor(rmax[j], off));
  float fac[4];
#pragma unroll
  for (int j = 0; j < 4; j++) {
    const float mn = fmaxf(mrow[j], rmax[j]);
    fac[j] = __expf(mrow[j] - mn);
    mrow[j] = mn;
  }
  float rsum[4] = {0.f, 0.f, 0.f, 0.f};
#pragma unroll
  for (int ct = 0; ct < 4; ct++)
#pragma unroll
    for (int j = 0; j < 4; j++) {
      const float pv = __expf(sc4[ct][j] - mrow[j]);
      sc4[ct][j] = pv;
      rsum[j] += pv;
    }
#pragma unroll
  for (int off = 1; off < 16; off <<= 1)
#pragma unroll
    for (int j = 0; j < 4; j++) rsum[j] += __shfl_xor(rsum[j], off);
#pragma unroll
  for (int j = 0; j < 4; j++) lrow[j] = lrow[j] * fac[j] + rsum[j];
#pragma unroll
  for (int ht = 0; ht < 4; ht++)
#pragma unroll
    for (int j = 0; j < 4; j++) oacc[ht][j] *= fac[j];
#pragma unroll
  for (int ct = 0; ct < 4; ct++)
#pragma unroll
    for (int j = 0; j < 4; j++)
      plw[(lg * 4 + j) * 72 + ct * 16 + lr] = (bf16_t)sc4[ct][j];
  bf16x8 pf[2];
#pragma unroll
  for (int sc = 0; sc < 2; sc++)
    pf[sc] = *reinterpret_cast<const bf16x8*>(&plw[lr * 72 + sc * 32 + lg * 8]);
#pragma unroll
  for (int ht = 0; ht < 4; ht++)
#pragma unroll
    for (int sc = 0; sc < 2; sc++) {
      const bf16x8 vf = *reinterpret_cast<const bf16x8*>(
          vg + (size_t)(ht * 16 + lr) * 2048 + cbase + sc * 32 + lg * 8);
      oacc[ht] = mfma16(pf[sc], vf, oacc[ht]);
    }
}

// ---------------------------------------------------------------------------
// Causal flash attention.  Paired Q-tiles (p, 31-p), XCD-pinned bh, no K/V
// staging (direct L2 reads), no barriers.  LDS = per-wave P buffer only.
// SPLIT=0: grid 512, full KV range.  SPLIT=1: grid 1024, split at kcut.
// ---------------------------------------------------------------------------
template <int SPLIT>
__global__ __launch_bounds__(256) void attn_kernel(
    const bf16_t* __restrict__ qk, const bf16_t* __restrict__ vT,
    bf16_t* __restrict__ ac, float* __restrict__ po,
    float* __restrict__ mlb) {
  const int f = blockIdx.x;
  const int bh = (f & 7) + 8 * ((f >> 3) & 3);   // same bh -> same XCD
  const int p = (f >> 5) & 15;
  const int half = SPLIT ? (f >> 9) : 0;
  const int qlo = p, qhi = 31 - p;
  const int nst = qhi + 1;
  const int kcut = SPLIT ? (p >= 7 ? 8 : 16 - p) : nst;
  const int st0 = half ? kcut : 0;
  const int st1 = half ? nst : kcut;
  const int b = bh >> 4, h = bh & 15;
  const int tid = threadIdx.x;
  const int l = tid & 63, w = tid >> 6;
  const int lr = l & 15, lg = l >> 4;

  __shared__ __align__(16) bf16_t pl[4][16 * 72];   // 9216 B total
  bf16_t* plw = pl[w];

  const bf16_t* qb = qk + ((size_t)(b * 2048 + w * 16 + lr)) * 2048 + h * 64;
  bf16x8 qfl[2], qfh[2];
#pragma unroll
  for (int kc = 0; kc < 2; kc++) {
    qfl[kc] = *(const bf16x8*)(qb + (size_t)qlo * 64 * 2048 + kc * 32 + lg * 8);
    qfh[kc] = *(const bf16x8*)(qb + (size_t)qhi * 64 * 2048 + kc * 32 + lg * 8);
  }

  f32x4 oaccl[4], oacch[4];
  float ml[4], llo[4], mh[4], lhi[4];
#pragma unroll
  for (int i = 0; i < 4; i++) { oaccl[i] = (f32x4)(0.f); oacch[i] = (f32x4)(0.f); }
#pragma unroll
  for (int j = 0; j < 4; j++) { ml[j] = -1e30f; llo[j] = 0.f; mh[j] = -1e30f; lhi[j] = 0.f; }

  const int rlo = qlo * 64 + w * 16 + lg * 4;
  const int rhi = qhi * 64 + w * 16 + lg * 4;

  const bf16_t* kg2 = qk + ((size_t)(b * 2048)) * 2048 + 1024 + h * 64;
  const bf16_t* vg = vT + ((size_t)(bh * 64)) * 2048;

  for (int st = st0; st < st1; ++st) {
    attn_tile(kg2, vg, st, plw, qfh, oacch, mh, lhi, lr, lg, rhi, st == qhi);
    if (st <= qlo)
      attn_tile(kg2, vg, st, plw, qfl, oaccl, ml, llo, lr, lg, rlo, st == qlo);
  }

  if constexpr (SPLIT == 0) {
#pragma unroll
    for (int ht = 0; ht < 4; ht++)
#pragma unroll
      for (int j = 0; j < 4; j++) {
        const size_t tl = (size_t)(b * 2048 + rlo + j);
        ac[tl * 1024 + h * 64 + ht * 16 + lr] = (bf16_t)(oaccl[ht][j] / llo[j]);
        const size_t th = (size_t)(b * 2048 + rhi + j);
        ac[th * 1024 + h * 64 + ht * 16 + lr] = (bf16_t)(oacch[ht][j] / lhi[j]);
      }
  } else {
    // partial O (unnormalized, f32): po[half][bh*2048 + row][64]
    float* poh = po + (size_t)half * 65536 * 64;
    const size_t base = (size_t)bh * 2048;
#pragma unroll
    for (int ht = 0; ht < 4; ht++)
#pragma unroll
      for (int j = 0; j < 4; j++) {
        poh[(base + rlo + j) * 64 + ht * 16 + lr] = oaccl[ht][j];
        poh[(base + rhi + j) * 64 + ht * 16 + lr] = oacch[ht][j];
      }
    if (lr == 0) {
      float2* mlh = (float2*)mlb + (size_t)half * 65536 + base;
#pragma unroll
      for (int j = 0; j < 4; j++) {
        mlh[rlo + j] = make_float2(ml[j], llo[j]);
        mlh[rhi + j] = make_float2(mh[j], lhi[j]);
      }
    }
  }
}

// ---------------------------------------------------------------------------
// Merge two split-KV halves: O = (O0*e^{m0-m} + O1*e^{m1-m}) / (l0*e^{m0-m}+...)
// ---------------------------------------------------------------------------
__global__ __launch_bounds__(256) void attn_combine(
    const float* __restrict__ po, const float* __restrict__ mlb,
    bf16_t* __restrict__ ac) {
  const int t = threadIdx.x;
  const int row = blockIdx.x * 16 + (t >> 4);
  const int hs4 = (t & 15) * 4;
  const size_t HALF = (size_t)65536 * 64;
  const float2 ml0 = ((const float2*)mlb)[row];
  const float2 ml1 = ((const float2*)mlb)[65536 + row];
  const float m = fmaxf(ml0.x, ml1.x);
  const float w0 = __expf(ml0.x - m), w1 = __expf(ml1.x - m);
  const float inv = 1.f / (ml0.y * w0 + ml1.y * w1);
  const float4 o0 = *(const float4*)(po + (size_t)row * 64 + hs4);
  const float4 o1 = *(const float4*)(po + HALF + (size_t)row * 64 + hs4);
  const int bh = row >> 11, qr = row & 2047;
  const int b = bh >> 4, h = bh & 15;
  bf16x4 o;
  o[0] = (bf16_t)((o0.x * w0 + o1.x * w1) * inv);
  o[1] = (bf16_t)((o0.y * w0 + o1.y * w1) * inv);
  o[2] = (bf16_t)((o0.z * w0 + o1.z * w1) * inv);
  o[3] = (bf16_t)((o0.w * w0 + o1.w * w1) * inv);
  *(bf16x4*)(ac + ((size_t)(b * 2048 + qr)) * 1024 + h * 64 + hs4) = o;
}

// ---------------------------------------------------------------------------
extern "C" void kernel_launch(void* const* d_in, const int* in_sizes, int n_in,
                              void* d_out, int out_size, void* d_ws, size_t ws_size,
                              hipStream_t stream) {
  const float* x     = (const float*)d_in[0];
  const float* wq    = (const float*)d_in[1];
  const float* wk    = (const float*)d_in[2];
  const float* wv    = (const float*)d_in[3];
  const float* wproj = (const float*)d_in[4];
  const float* bproj = (const float*)d_in[5];
  const float* w1    = (const float*)d_in[6];
  const float* b1    = (const float*)d_in[7];
  const float* w2    = (const float*)d_in[8];
  const float* b2    = (const float*)d_in[9];
  const float* ln1g  = (const float*)d_in[10];
  const float* ln1b  = (const float*)d_in[11];
  const float* ln2g  = (const float*)d_in[12];
  const float* ln2b  = (const float*)d_in[13];
  float* out = (float*)d_out;

  char* ws = (char*)d_ws;
  const size_t MB = 1 << 20;
  bf16_t* xn  = (bf16_t*)(ws + 0);         // 8 MB  (reused as hn after LN2)
  bf16_t* wT  = (bf16_t*)(ws + 8 * MB);    // 8 MB  weight-transpose slot
  float*  hbuf= (float*)(ws + 16 * MB);    // 16 MB residual h (f32)
  bf16_t* qkb = (bf16_t*)(ws + 32 * MB);   // 16 MB q|k  [4096][2048]
  bf16_t* vTb = (bf16_t*)(ws + 48 * MB);   // 8 MB  v^T
  bf16_t* acb = (bf16_t*)(ws + 56 * MB);   // 8 MB  attn concat
  bf16_t* ffa = (bf16_t*)(ws + 32 * MB);   // 32 MB ff1 act (reuses qk/vT/ac)
  float*  part= (float*)(ws + 64 * MB);    // 64 MB split-K partials (big path)
  float*  po  = (float*)(ws + 64 * MB);    // 32 MB attn O partials (pre-proj)
  float*  mlb = (float*)(ws + 96 * MB);    // 1 MB  attn (m,l) partials
  bf16_t* hn  = xn;

  const bool big = ws_size >= 128 * MB;
  dim3 tb(32, 8);

  ln_kernel<<<4096, 256, 0, stream>>>(x, ln1g, ln1b, xn);
  transpose_cvt<<<dim3(2, 32, 16), tb, 0, stream>>>(wq, wT, 1024, 64);
  transpose_cvt<<<dim3(2, 32, 16), tb, 0, stream>>>(wk, wT + 1024 * 1024, 1024, 64);
  transpose_cvt<<<dim3(2, 32, 16), tb, 0, stream>>>(wv, wT + 2048 * 1024, 1024, 64);
  gemm_bt<0><<<dim3(24, 32), 256, 0, stream>>>(xn, wT, nullptr, nullptr, qkb, vTb,
                                               4096, 3072, 1024);
  if (big) {
    attn_kernel<1><<<1024, 256, 0, stream>>>(qkb, vTb, acb, po, mlb);
    attn_combine<<<4096, 256, 0, stream>>>(po, mlb, acb);
  } else {
    attn_kernel<0><<<512, 256, 0, stream>>>(qkb, vTb, acb, nullptr, nullptr);
  }
  transpose_cvt<<<dim3(32, 32, 1), tb, 0, stream>>>(wproj, wT, 1024, 1024);
  if (big) {
    gemm_bt<3><<<dim3(8, 32, 2), 256, 0, stream>>>(acb, wT, nullptr, nullptr,
                                                   part, nullptr, 4096, 1024, 1024);
    ln2_red_kernel<<<4096, 256, 0, stream>>>(part, bproj, x, ln2g, ln2b, hbuf, hn);
  } else {
    gemm_bt<1><<<dim3(8, 32), 256, 0, stream>>>(acb, wT, bproj, x, hbuf, nullptr,
                                                4096, 1024, 1024);
    ln_kernel<<<4096, 256, 0, stream>>>(hbuf, ln2g, ln2b, hn);
  }
  transpose_cvt<<<dim3(128, 32, 1), tb, 0, stream>>>(w1, wT, 1024, 4096);
  gemm_bt<2><<<dim3(32, 32), 256, 0, stream>>>(hn, wT, b1, nullptr, ffa, nullptr,
                                               4096, 4096, 1024);
  transpose_cvt<<<dim3(32, 128, 1), tb, 0, stream>>>(w2, wT, 4096, 1024);
  if (big) {
    gemm_bt<3><<<dim3(8, 32, 4), 256, 0, stream>>>(ffa, wT, nullptr, nullptr,
                                                   part, nullptr, 4096, 1024, 4096);
    red4_kernel<<<4096, 256, 0, stream>>>(part, b2, hbuf, out);
  } else {
    gemm_bt<1><<<dim3(8, 32), 256, 0, stream>>>(ffa, wT, b2, hbuf, out, nullptr,
                                                4096, 1024, 4096);
  }
}

// Round 10
// 420.891 us; speedup vs baseline: 1.0687x; 1.0687x over previous
//
#include <hip/hip_runtime.h>

// ---------------------------------------------------------------------------
// AttentionThinkingBlock: LN1 -> QKV -> causal attn -> proj+res -> LN2 -> MLP
// B=2, S=2048, D=1024, H=16, HS=64.  All internal matmuls in bf16 MFMA.
// Round 10: attn co-residency was register-capped (~144 unified VGPR+AGPR
// > 128 -> 2 blocks/CU across ALL prior variants).  Fix: single-Q-tile
// blocks (half the live state) + split-KV-2 (grid 2048, <=16 tiles/block)
// + __launch_bounds__(256,4) to force <=128 regs -> 4 blocks/CU.
// Staging restored (R7 proved direct-L2 reads slower).
// ---------------------------------------------------------------------------

typedef __bf16 bf16_t;
typedef __attribute__((ext_vector_type(8))) __bf16 bf16x8;
typedef __attribute__((ext_vector_type(4))) __bf16 bf16x4;
typedef __attribute__((ext_vector_type(4))) float f32x4;

__device__ __forceinline__ f32x4 mfma16(bf16x8 a, bf16x8 b, f32x4 c) {
  return __builtin_amdgcn_mfma_f32_16x16x32_bf16(a, b, c, 0, 0, 0);
}

__device__ __forceinline__ void gll16(const void* g, void* l) {
  __builtin_amdgcn_global_load_lds(
      (const __attribute__((address_space(1))) void*)g,
      (__attribute__((address_space(3))) void*)l, 16, 0, 0);
}

// ---------------------------------------------------------------------------
// LayerNorm (f32 in) -> bf16 out.  One block per row, D=1024.
// ---------------------------------------------------------------------------
__global__ __launch_bounds__(256) void ln_kernel(
    const float* __restrict__ x, const float* __restrict__ g,
    const float* __restrict__ be, bf16_t* __restrict__ out) {
  const int row = blockIdx.x;
  const int tid = threadIdx.x;
  const float4 v = *(reinterpret_cast<const float4*>(x + (size_t)row * 1024) + tid);
  float s1 = v.x + v.y + v.z + v.w;
  float s2 = v.x * v.x + v.y * v.y + v.z * v.z + v.w * v.w;
#pragma unroll
  for (int off = 1; off < 64; off <<= 1) {
    s1 += __shfl_xor(s1, off);
    s2 += __shfl_xor(s2, off);
  }
  __shared__ float red[8];
  const int l = tid & 63, w = tid >> 6;
  if (l == 0) { red[w] = s1; red[w + 4] = s2; }
  __syncthreads();
  s1 = red[0] + red[1] + red[2] + red[3];
  s2 = red[4] + red[5] + red[6] + red[7];
  const float mu = s1 * (1.f / 1024.f);
  const float var = s2 * (1.f / 1024.f) - mu * mu;
  const float rstd = rsqrtf(var + 1e-5f);
  const float4 gg = *(reinterpret_cast<const float4*>(g) + tid);
  const float4 bb = *(reinterpret_cast<const float4*>(be) + tid);
  bf16x4 o;
  o[0] = (bf16_t)((v.x - mu) * rstd * gg.x + bb.x);
  o[1] = (bf16_t)((v.y - mu) * rstd * gg.y + bb.y);
  o[2] = (bf16_t)((v.z - mu) * rstd * gg.z + bb.z);
  o[3] = (bf16_t)((v.w - mu) * rstd * gg.w + bb.w);
  *(reinterpret_cast<bf16x4*>(out + (size_t)row * 1024) + tid) = o;
}

// ---------------------------------------------------------------------------
// Fused: h = p0 + p1 + bproj + x  (proj split-K reduce) -> hbuf f32, then LN2.
// ---------------------------------------------------------------------------
__global__ __launch_bounds__(256) void ln2_red_kernel(
    const float* __restrict__ p, const float* __restrict__ bp,
    const float* __restrict__ x, const float* __restrict__ g,
    const float* __restrict__ be, float* __restrict__ hb,
    bf16_t* __restrict__ out) {
  const size_t PM = (size_t)4096 * 1024;
  const int row = blockIdx.x;
  const int tid = threadIdx.x;
  const size_t ro = (size_t)row * 1024;
  float4 v = *(reinterpret_cast<const float4*>(p + ro) + tid);
  const float4 v1 = *(reinterpret_cast<const float4*>(p + PM + ro) + tid);
  const float4 vb = *(reinterpret_cast<const float4*>(bp) + tid);
  const float4 vx = *(reinterpret_cast<const float4*>(x + ro) + tid);
  v.x += v1.x + vb.x + vx.x; v.y += v1.y + vb.y + vx.y;
  v.z += v1.z + vb.z + vx.z; v.w += v1.w + vb.w + vx.w;
  *(reinterpret_cast<float4*>(hb + ro) + tid) = v;
  float s1 = v.x + v.y + v.z + v.w;
  float s2 = v.x * v.x + v.y * v.y + v.z * v.z + v.w * v.w;
#pragma unroll
  for (int off = 1; off < 64; off <<= 1) {
    s1 += __shfl_xor(s1, off);
    s2 += __shfl_xor(s2, off);
  }
  __shared__ float red[8];
  const int l = tid & 63, w = tid >> 6;
  if (l == 0) { red[w] = s1; red[w + 4] = s2; }
  __syncthreads();
  s1 = red[0] + red[1] + red[2] + red[3];
  s2 = red[4] + red[5] + red[6] + red[7];
  const float mu = s1 * (1.f / 1024.f);
  const float var = s2 * (1.f / 1024.f) - mu * mu;
  const float rstd = rsqrtf(var + 1e-5f);
  const float4 gg = *(reinterpret_cast<const float4*>(g) + tid);
  const float4 bb = *(reinterpret_cast<const float4*>(be) + tid);
  bf16x4 o;
  o[0] = (bf16_t)((v.x - mu) * rstd * gg.x + bb.x);
  o[1] = (bf16_t)((v.y - mu) * rstd * gg.y + bb.y);
  o[2] = (bf16_t)((v.z - mu) * rstd * gg.z + bb.z);
  o[3] = (bf16_t)((v.w - mu) * rstd * gg.w + bb.w);
  *(reinterpret_cast<bf16x4*>(out + ro) + tid) = o;
}

// ---------------------------------------------------------------------------
// FF2 split-K reduce: out = p0+p1+p2+p3 + b2 + hbuf.
// ---------------------------------------------------------------------------
__global__ __launch_bounds__(256) void red4_kernel(
    const float* __restrict__ p, const float* __restrict__ b2,
    const float* __restrict__ hb, float* __restrict__ out) {
  const size_t PM = (size_t)4096 * 1024;
  const int row = blockIdx.x;
  const int tid = threadIdx.x;
  const size_t ro = (size_t)row * 1024;
  float4 v = *(reinterpret_cast<const float4*>(p + ro) + tid);
#pragma unroll
  for (int s = 1; s < 4; s++) {
    const float4 vs = *(reinterpret_cast<const float4*>(p + s * PM + ro) + tid);
    v.x += vs.x; v.y += vs.y; v.z += vs.z; v.w += vs.w;
  }
  const float4 vb = *(reinterpret_cast<const float4*>(b2) + tid);
  const float4 vh = *(reinterpret_cast<const float4*>(hb + ro) + tid);
  v.x += vb.x + vh.x; v.y += vb.y + vh.y;
  v.z += vb.z + vh.z; v.w += vb.w + vh.w;
  *(reinterpret_cast<float4*>(out + ro) + tid) = v;
}

// ---------------------------------------------------------------------------
// Batched transpose+convert: in f32 [bz][R][C] -> out bf16 [bz][C][R]
// ---------------------------------------------------------------------------
__global__ __launch_bounds__(256) void transpose_cvt(
    const float* __restrict__ in, bf16_t* __restrict__ out, int R, int C) {
  __shared__ float t[32][33];
  const int bz = blockIdx.z;
  in += (size_t)bz * R * C;
  out += (size_t)bz * R * C;
  const int c0 = blockIdx.x * 32, r0 = blockIdx.y * 32;
  const int tx = threadIdx.x, ty = threadIdx.y;
#pragma unroll
  for (int i = 0; i < 4; i++)
    t[ty + i * 8][tx] = in[(size_t)(r0 + ty + i * 8) * C + c0 + tx];
  __syncthreads();
#pragma unroll
  for (int i = 0; i < 4; i++)
    out[(size_t)(c0 + ty + i * 8) * R + r0 + tx] = (bf16_t)t[tx][ty + i * 8];
}

// ---------------------------------------------------------------------------
// GEMM C[M,N] = A[M,K] @ B^T[N,K]  (m97 structure + XCD-aware block swizzle)
// MODE 0 = QKV epilogue  MODE 1 = f32 out = acc+bias+resid  MODE 2 = relu bf16
// MODE 3 = split-K partial (blockIdx.z chunk -> out0 + z*M*N)
// ---------------------------------------------------------------------------
template <int MODE>
__global__ __launch_bounds__(256) void gemm_bt(
    const bf16_t* __restrict__ A, const bf16_t* __restrict__ BT,
    const float* __restrict__ bias, const float* __restrict__ resid,
    void* __restrict__ out0, void* __restrict__ out1, int M, int N, int K) {
  __shared__ __align__(16) bf16_t Al[128 * 32];
  __shared__ __align__(16) bf16_t Bl[128 * 32];
  const int tid = threadIdx.x;
  const int l = tid & 63, w = tid >> 6;
  const int wr = w >> 1, wc = w & 1;
  const int lr = l & 15, lg = l >> 4;
  const int gx = gridDim.x;
  const int nwg = gx * gridDim.y;
  int flat = blockIdx.y * gx + blockIdx.x;
  flat = (flat & 7) * (nwg >> 3) + (flat >> 3);
  const int bm = (flat / gx) * 128, bn = (flat % gx) * 128;

  int k0 = 0, nK = K >> 5;
  if constexpr (MODE == 3) {
    const int chunk = K / gridDim.z;
    k0 = blockIdx.z * chunk;
    nK = chunk >> 5;
  }

  f32x4 acc[4][4];
#pragma unroll
  for (int i = 0; i < 4; i++)
#pragma unroll
    for (int j = 0; j < 4; j++) acc[i][j] = (f32x4)(0.f);

  const char* Ag = (const char*)(A + (size_t)bm * K + k0);
  const char* Bg = (const char*)(BT + (size_t)bn * K + k0);
  const size_t rowb = (size_t)K * 2;

  for (int kt = 0; kt < nK; ++kt) {
#pragma unroll
    for (int i = 0; i < 2; i++) {
      const int s = i * 256 + tid;
      const size_t go = (size_t)(s >> 2) * rowb + (size_t)(kt * 64 + (s & 3) * 16);
      gll16(Ag + go, (char*)Al + (i * 256 + w * 64) * 16);
      gll16(Bg + go, (char*)Bl + (i * 256 + w * 64) * 16);
    }
    __syncthreads();
    bf16x8 af[4], bfr[4];
#pragma unroll
    for (int mi = 0; mi < 4; mi++)
      af[mi] = *reinterpret_cast<const bf16x8*>(Al + (wr * 64 + mi * 16 + lr) * 32 + lg * 8);
#pragma unroll
    for (int ni = 0; ni < 4; ni++)
      bfr[ni] = *reinterpret_cast<const bf16x8*>(Bl + (wc * 64 + ni * 16 + lr) * 32 + lg * 8);
#pragma unroll
    for (int mi = 0; mi < 4; mi++)
#pragma unroll
      for (int ni = 0; ni < 4; ni++)
        acc[mi][ni] = mfma16(af[mi], bfr[ni], acc[mi][ni]);
    __syncthreads();
  }

#pragma unroll
  for (int mi = 0; mi < 4; mi++) {
    const int r = bm + wr * 64 + mi * 16 + lg * 4;
#pragma unroll
    for (int ni = 0; ni < 4; ni++) {
      const int c = bn + wc * 64 + ni * 16 + lr;
      f32x4 v = acc[mi][ni];
      if constexpr (MODE == 1) {
        const float bb = bias[c];
        float* o = (float*)out0;
#pragma unroll
        for (int j = 0; j < 4; j++)
          o[(size_t)(r + j) * N + c] = v[j] + bb + resid[(size_t)(r + j) * N + c];
      } else if constexpr (MODE == 2) {
        const float bb = bias[c];
        bf16_t* o = (bf16_t*)out0;
#pragma unroll
        for (int j = 0; j < 4; j++)
          o[(size_t)(r + j) * N + c] = (bf16_t)fmaxf(v[j] + bb, 0.f);
      } else if constexpr (MODE == 3) {
        float* o = (float*)out0 + (size_t)blockIdx.z * M * N;
#pragma unroll
        for (int j = 0; j < 4; j++)
          o[(size_t)(r + j) * N + c] = v[j];
      } else {
        if (c < 2048) {
          bf16_t* o = (bf16_t*)out0;
#pragma unroll
          for (int j = 0; j < 4; j++)
            o[(size_t)(r + j) * 2048 + c] = (bf16_t)v[j];
        } else {
          const int nn = c - 2048;
          const int bI = r >> 11, tl = r & 2047;
          bf16x4 pk;
#pragma unroll
          for (int j = 0; j < 4; j++) pk[j] = (bf16_t)v[j];
          *reinterpret_cast<bf16x4*>((bf16_t*)out1 +
              ((size_t)(bI * 1024 + nn)) * 2048 + tl) = pk;
        }
      }
    }
  }
}

// ---------------------------------------------------------------------------
// One K-tile of flash attention for one wave's 16 Q-rows (staged LDS tiles).
// ---------------------------------------------------------------------------
__device__ __forceinline__ void attn_tile(
    const bf16_t* __restrict__ kl, const bf16_t* __restrict__ vl,
    bf16_t* __restrict__ plw, const bf16x8* qf, f32x4* oacc,
    float* mrow, float* lrow, const int lr, const int lg,
    const int rbase, const int cbase, const bool diag) {
  f32x4 sc4[4];
#pragma unroll
  for (int ct = 0; ct < 4; ct++) sc4[ct] = (f32x4)(0.f);
#pragma unroll
  for (int ct = 0; ct < 4; ct++)
#pragma unroll
    for (int kc = 0; kc < 2; kc++) {
      bf16x8 kf = *reinterpret_cast<const bf16x8*>(
          &kl[(ct * 16 + lr) * 72 + kc * 32 + lg * 8]);
      sc4[ct] = mfma16(qf[kc], kf, sc4[ct]);
    }
#pragma unroll
  for (int ct = 0; ct < 4; ct++)
#pragma unroll
    for (int j = 0; j < 4; j++) {
      float sv = sc4[ct][j] * 0.125f;
      if (diag && (cbase + ct * 16 + lr > rbase + j)) sv = -1e30f;
      sc4[ct][j] = sv;
    }
  float rmax[4];
#pragma unroll
  for (int j = 0; j < 4; j++)
    rmax[j] = fmaxf(fmaxf(sc4[0][j], sc4[1][j]), fmaxf(sc4[2][j], sc4[3][j]));
#pragma unroll
  for (int off = 1; off < 16; off <<= 1)
#pragma unroll
    for (int j = 0; j < 4; j++) rmax[j] = fmaxf(rmax[j], __shfl_xor(rmax[j], off));
  float fac[4];
#pragma unroll
  for (int j = 0; j < 4; j++) {
    const float mn = fmaxf(mrow[j], rmax[j]);
    fac[j] = __expf(mrow[j] - mn);
    mrow[j] = mn;
  }
  float rsum[4] = {0.f, 0.f, 0.f, 0.f};
#pragma unroll
  for (int ct = 0; ct < 4; ct++)
#pragma unroll
    for (int j = 0; j < 4; j++) {
      const float pv = __expf(sc4[ct][j] - mrow[j]);
      sc4[ct][j] = pv;
      rsum[j] += pv;
    }
#pragma unroll
  for (int off = 1; off < 16; off <<= 1)
#pragma unroll
    for (int j = 0; j < 4; j++) rsum[j] += __shfl_xor(rsum[j], off);
#pragma unroll
  for (int j = 0; j < 4; j++) lrow[j] = lrow[j] * fac[j] + rsum[j];
#pragma unroll
  for (int ht = 0; ht < 4; ht++)
#pragma unroll
    for (int j = 0; j < 4; j++) oacc[ht][j] *= fac[j];
#pragma unroll
  for (int ct = 0; ct < 4; ct++)
#pragma unroll
    for (int j = 0; j < 4; j++)
      plw[(lg * 4 + j) * 72 + ct * 16 + lr] = (bf16_t)sc4[ct][j];
  bf16x8 pf[2];
#pragma unroll
  for (int sc = 0; sc < 2; sc++)
    pf[sc] = *reinterpret_cast<const bf16x8*>(&plw[lr * 72 + sc * 32 + lg * 8]);
#pragma unroll
  for (int ht = 0; ht < 4; ht++)
#pragma unroll
    for (int sc = 0; sc < 2; sc++) {
      bf16x8 vf = *reinterpret_cast<const bf16x8*>(
          &vl[(ht * 16 + lr) * 72 + sc * 32 + lg * 8]);
      oacc[ht] = mfma16(pf[sc], vf, oacc[ht]);
    }
}

// ---------------------------------------------------------------------------
// Split-KV attention, single Q-tile per block, register-capped for 4 blk/CU.
// grid (32 bh, 32 qt, 2 half); block (bh,qt,half) does KV tiles
// [0,kcut) or [kcut,qt+1), kcut=ceil((qt+1)/2).  Writes partial (O,m,l).
// ---------------------------------------------------------------------------
__global__ __launch_bounds__(256, 4) void attn_split_kernel(
    const bf16_t* __restrict__ qk, const bf16_t* __restrict__ vT,
    float* __restrict__ po, float* __restrict__ mlb) {
  const int bh = blockIdx.x;           // bh%8 -> XCD pinning (4 heads/XCD)
  const int qt = blockIdx.y;
  const int half = blockIdx.z;
  const int nst = qt + 1;
  const int kcut = (qt + 2) >> 1;
  const int st0 = half ? kcut : 0;
  const int st1 = half ? nst : kcut;
  if (st0 >= st1) return;              // qt=0 half=1: empty (combine is safe)
  const int b = bh >> 4, h = bh & 15;
  const int tid = threadIdx.x;
  const int l = tid & 63, w = tid >> 6;
  const int lr = l & 15, lg = l >> 4;

  __shared__ __align__(16) bf16_t kl[64 * 72];
  __shared__ __align__(16) bf16_t vl[64 * 72];
  __shared__ __align__(16) bf16_t pl[4][16 * 72];
  bf16_t* plw = pl[w];

  const bf16_t* qb = qk + ((size_t)(b * 2048 + qt * 64 + w * 16 + lr)) * 2048 + h * 64;
  bf16x8 qf[2];
  qf[0] = *(const bf16x8*)(qb + lg * 8);
  qf[1] = *(const bf16x8*)(qb + 32 + lg * 8);

  f32x4 oacc[4];
  float mrow[4], lrow[4];
#pragma unroll
  for (int i = 0; i < 4; i++) oacc[i] = (f32x4)(0.f);
#pragma unroll
  for (int j = 0; j < 4; j++) { mrow[j] = -1e30f; lrow[j] = 0.f; }

  const int rbase = qt * 64 + w * 16 + lg * 4;

  const int r0 = tid >> 3, c0 = (tid & 7) * 8;
  const bf16_t* kg = qk + ((size_t)(b * 2048)) * 2048 + 1024 + h * 64;
  const bf16_t* vg = vT + ((size_t)(bh * 64)) * 2048;

  bf16x8 kreg[2], vreg[2];
#pragma unroll
  for (int i = 0; i < 2; i++) {
    const int r = r0 + i * 32;
    kreg[i] = *(const bf16x8*)(kg + (size_t)(st0 * 64 + r) * 2048 + c0);
    vreg[i] = *(const bf16x8*)(vg + (size_t)r * 2048 + st0 * 64 + c0);
  }

  for (int st = st0; st < st1; ++st) {
    __syncthreads();
#pragma unroll
    for (int i = 0; i < 2; i++) {
      const int r = r0 + i * 32;
      *(bf16x8*)(&kl[r * 72 + c0]) = kreg[i];
      *(bf16x8*)(&vl[r * 72 + c0]) = vreg[i];
    }
    __syncthreads();
    if (st + 1 < st1) {
#pragma unroll
      for (int i = 0; i < 2; i++) {
        const int r = r0 + i * 32;
        kreg[i] = *(const bf16x8*)(kg + (size_t)((st + 1) * 64 + r) * 2048 + c0);
        vreg[i] = *(const bf16x8*)(vg + (size_t)r * 2048 + (st + 1) * 64 + c0);
      }
    }
    attn_tile(kl, vl, plw, qf, oacc, mrow, lrow, lr, lg, rbase, st * 64, st == qt);
  }

  // partial epilogue: po[half][bh*2048 + row][64], mlb[half][bh*2048 + row]
  float* poh = po + (size_t)half * 65536 * 64;
  const size_t base = (size_t)bh * 2048;
#pragma unroll
  for (int ht = 0; ht < 4; ht++)
#pragma unroll
    for (int j = 0; j < 4; j++)
      poh[(base + rbase + j) * 64 + ht * 16 + lr] = oacc[ht][j];
  if (lr == 0) {
    float2* mlh = (float2*)mlb + (size_t)half * 65536 + base;
#pragma unroll
    for (int j = 0; j < 4; j++) mlh[rbase + j] = make_float2(mrow[j], lrow[j]);
  }
}

// ---------------------------------------------------------------------------
// Fallback: R4 paired-Q staged attention (grid 512), writes ac directly.
// ---------------------------------------------------------------------------
__global__ __launch_bounds__(256) void attn_pair_kernel(
    const bf16_t* __restrict__ qk, const bf16_t* __restrict__ vT,
    bf16_t* __restrict__ ac) {
  const int f = blockIdx.x;
  const int bh = (f & 7) + 8 * ((f >> 3) & 3);
  const int p = f >> 5;
  const int qlo = p, qhi = 31 - p;
  const int b = bh >> 4, h = bh & 15;
  const int tid = threadIdx.x;
  const int l = tid & 63, w = tid >> 6;
  const int lr = l & 15, lg = l >> 4;

  __shared__ __align__(16) bf16_t kl[64 * 72];
  __shared__ __align__(16) bf16_t vl[64 * 72];
  __shared__ __align__(16) bf16_t pl[4][16 * 72];
  bf16_t* plw = pl[w];

  const bf16_t* qb = qk + ((size_t)(b * 2048 + w * 16 + lr)) * 2048 + h * 64;
  bf16x8 qfl[2], qfh[2];
#pragma unroll
  for (int kc = 0; kc < 2; kc++) {
    qfl[kc] = *(const bf16x8*)(qb + (size_t)qlo * 64 * 2048 + kc * 32 + lg * 8);
    qfh[kc] = *(const bf16x8*)(qb + (size_t)qhi * 64 * 2048 + kc * 32 + lg * 8);
  }

  f32x4 oaccl[4], oacch[4];
  float ml[4], llo[4], mh[4], lhi[4];
#pragma unroll
  for (int i = 0; i < 4; i++) { oaccl[i] = (f32x4)(0.f); oacch[i] = (f32x4)(0.f); }
#pragma unroll
  for (int j = 0; j < 4; j++) { ml[j] = -1e30f; llo[j] = 0.f; mh[j] = -1e30f; lhi[j] = 0.f; }

  const int rlo = qlo * 64 + w * 16 + lg * 4;
  const int rhi = qhi * 64 + w * 16 + lg * 4;

  const int r0 = tid >> 3, c0 = (tid & 7) * 8;
  const bf16_t* kg = qk + ((size_t)(b * 2048)) * 2048 + 1024 + h * 64;
  const bf16_t* vg = vT + ((size_t)(bh * 64)) * 2048;

  bf16x8 kreg[2], vreg[2];
#pragma unroll
  for (int i = 0; i < 2; i++) {
    const int r = r0 + i * 32;
    kreg[i] = *(const bf16x8*)(kg + (size_t)r * 2048 + c0);
    vreg[i] = *(const bf16x8*)(vg + (size_t)r * 2048 + c0);
  }

  const int nst = qhi + 1;
  for (int st = 0; st < nst; ++st) {
    __syncthreads();
#pragma unroll
    for (int i = 0; i < 2; i++) {
      const int r = r0 + i * 32;
      *(bf16x8*)(&kl[r * 72 + c0]) = kreg[i];
      *(bf16x8*)(&vl[r * 72 + c0]) = vreg[i];
    }
    __syncthreads();
    if (st + 1 < nst) {
#pragma unroll
      for (int i = 0; i < 2; i++) {
        const int r = r0 + i * 32;
        kreg[i] = *(const bf16x8*)(kg + (size_t)((st + 1) * 64 + r) * 2048 + c0);
        vreg[i] = *(const bf16x8*)(vg + (size_t)r * 2048 + (st + 1) * 64 + c0);
      }
    }
    attn_tile(kl, vl, plw, qfh, oacch, mh, lhi, lr, lg, rhi, st * 64, st == qhi);
    if (st <= qlo)
      attn_tile(kl, vl, plw, qfl, oaccl, ml, llo, lr, lg, rlo, st * 64, st == qlo);
  }

#pragma unroll
  for (int ht = 0; ht < 4; ht++)
#pragma unroll
    for (int j = 0; j < 4; j++) {
      const size_t tl = (size_t)(b * 2048 + rlo + j);
      ac[tl * 1024 + h * 64 + ht * 16 + lr] = (bf16_t)(oaccl[ht][j] / llo[j]);
      const size_t th = (size_t)(b * 2048 + rhi + j);
      ac[th * 1024 + h * 64 + ht * 16 + lr] = (bf16_t)(oacch[ht][j] / lhi[j]);
    }
}

// ---------------------------------------------------------------------------
// Merge two split-KV halves: O = (O0*e^{m0-m} + O1*e^{m1-m}) / (l0*e^{m0-m}+...)
// ---------------------------------------------------------------------------
__global__ __launch_bounds__(256) void attn_combine(
    const float* __restrict__ po, const float* __restrict__ mlb,
    bf16_t* __restrict__ ac) {
  const int t = threadIdx.x;
  const int row = blockIdx.x * 16 + (t >> 4);
  const int hs4 = (t & 15) * 4;
  const size_t HALF = (size_t)65536 * 64;
  const float2 ml0 = ((const float2*)mlb)[row];
  const float2 ml1 = ((const float2*)mlb)[65536 + row];
  const float m = fmaxf(ml0.x, ml1.x);
  const float w0 = __expf(ml0.x - m), w1 = __expf(ml1.x - m);
  const float inv = 1.f / (ml0.y * w0 + ml1.y * w1);
  const float4 o0 = *(const float4*)(po + (size_t)row * 64 + hs4);
  const float4 o1 = *(const float4*)(po + HALF + (size_t)row * 64 + hs4);
  const int bh = row >> 11, qr = row & 2047;
  const int b = bh >> 4, h = bh & 15;
  bf16x4 o;
  o[0] = (bf16_t)((o0.x * w0 + o1.x * w1) * inv);
  o[1] = (bf16_t)((o0.y * w0 + o1.y * w1) * inv);
  o[2] = (bf16_t)((o0.z * w0 + o1.z * w1) * inv);
  o[3] = (bf16_t)((o0.w * w0 + o1.w * w1) * inv);
  *(bf16x4*)(ac + ((size_t)(b * 2048 + qr)) * 1024 + h * 64 + hs4) = o;
}

// ---------------------------------------------------------------------------
extern "C" void kernel_launch(void* const* d_in, const int* in_sizes, int n_in,
                              void* d_out, int out_size, void* d_ws, size_t ws_size,
                              hipStream_t stream) {
  const float* x     = (const float*)d_in[0];
  const float* wq    = (const float*)d_in[1];
  const float* wk    = (const float*)d_in[2];
  const float* wv    = (const float*)d_in[3];
  const float* wproj = (const float*)d_in[4];
  const float* bproj = (const float*)d_in[5];
  const float* w1    = (const float*)d_in[6];
  const float* b1    = (const float*)d_in[7];
  const float* w2    = (const float*)d_in[8];
  const float* b2    = (const float*)d_in[9];
  const float* ln1g  = (const float*)d_in[10];
  const float* ln1b  = (const float*)d_in[11];
  const float* ln2g  = (const float*)d_in[12];
  const float* ln2b  = (const float*)d_in[13];
  float* out = (float*)d_out;

  char* ws = (char*)d_ws;
  const size_t MB = 1 << 20;
  bf16_t* xn  = (bf16_t*)(ws + 0);         // 8 MB  (reused as hn after LN2)
  bf16_t* wT  = (bf16_t*)(ws + 8 * MB);    // 8 MB  weight-transpose slot
  float*  hbuf= (float*)(ws + 16 * MB);    // 16 MB residual h (f32)
  bf16_t* qkb = (bf16_t*)(ws + 32 * MB);   // 16 MB q|k  [4096][2048]
  bf16_t* vTb = (bf16_t*)(ws + 48 * MB);   // 8 MB  v^T
  bf16_t* acb = (bf16_t*)(ws + 56 * MB);   // 8 MB  attn concat
  bf16_t* ffa = (bf16_t*)(ws + 32 * MB);   // 32 MB ff1 act (reuses qk/vT/ac)
  float*  part= (float*)(ws + 64 * MB);    // 64 MB split-K partials (big path)
  float*  po  = (float*)(ws + 64 * MB);    // 32 MB attn O partials (pre-proj)
  float*  mlb = (float*)(ws + 96 * MB);    // 1 MB  attn (m,l) partials
  bf16_t* hn  = xn;

  const bool big = ws_size >= 128 * MB;
  dim3 tb(32, 8);

  ln_kernel<<<4096, 256, 0, stream>>>(x, ln1g, ln1b, xn);
  transpose_cvt<<<dim3(2, 32, 16), tb, 0, stream>>>(wq, wT, 1024, 64);
  transpose_cvt<<<dim3(2, 32, 16), tb, 0, stream>>>(wk, wT + 1024 * 1024, 1024, 64);
  transpose_cvt<<<dim3(2, 32, 16), tb, 0, stream>>>(wv, wT + 2048 * 1024, 1024, 64);
  gemm_bt<0><<<dim3(24, 32), 256, 0, stream>>>(xn, wT, nullptr, nullptr, qkb, vTb,
                                               4096, 3072, 1024);
  if (big) {
    attn_split_kernel<<<dim3(32, 32, 2), 256, 0, stream>>>(qkb, vTb, po, mlb);
    attn_combine<<<4096, 256, 0, stream>>>(po, mlb, acb);
  } else {
    attn_pair_kernel<<<512, 256, 0, stream>>>(qkb, vTb, acb);
  }
  transpose_cvt<<<dim3(32, 32, 1), tb, 0, stream>>>(wproj, wT, 1024, 1024);
  if (big) {
    gemm_bt<3><<<dim3(8, 32, 2), 256, 0, stream>>>(acb, wT, nullptr, nullptr,
                                                   part, nullptr, 4096, 1024, 1024);
    ln2_red_kernel<<<4096, 256, 0, stream>>>(part, bproj, x, ln2g, ln2b, hbuf, hn);
  } else {
    gemm_bt<1><<<dim3(8, 32), 256, 0, stream>>>(acb, wT, bproj, x, hbuf, nullptr,
                                                4096, 1024, 1024);
    ln_kernel<<<4096, 256, 0, stream>>>(hbuf, ln2g, ln2b, hn);
  }
  transpose_cvt<<<dim3(128, 32, 1), tb, 0, stream>>>(w1, wT, 1024, 4096);
  gemm_bt<2><<<dim3(32, 32), 256, 0, stream>>>(hn, wT, b1, nullptr, ffa, nullptr,
                                               4096, 4096, 1024);
  transpose_cvt<<<dim3(32, 128, 1), tb, 0, stream>>>(w2, wT, 4096, 1024);
  if (big) {
    gemm_bt<3><<<dim3(8, 32, 4), 256, 0, stream>>>(ffa, wT, nullptr, nullptr,
                                                   part, nullptr, 4096, 1024, 4096);
    red4_kernel<<<4096, 256, 0, stream>>>(part, b2, hbuf, out);
  } else {
    gemm_bt<1><<<dim3(8, 32), 256, 0, stream>>>(ffa, wT, b2, hbuf, out, nullptr,
                                                4096, 1024, 4096);
  }
}